// Round 1
// baseline (408.596 us; speedup 1.0000x reference)
//
#include <hip/hip_runtime.h>

// Point Transformer block, MI355X/gfx950.
// B=4, N=8192, K=16, D=128.
#define NB 4
#define NN 8192
#define NK 16
#define ND 128
#define NPTS (NB*NN)   // 32768 points

typedef __bf16 bv8 __attribute__((ext_vector_type(8)));
typedef unsigned short us8 __attribute__((ext_vector_type(8)));
typedef float fv4 __attribute__((ext_vector_type(4)));

__device__ __forceinline__ unsigned short f2b(float x){
  union { float f; unsigned u; } v; v.f = x;
  unsigned r = v.u + 0x7FFFu + ((v.u >> 16) & 1u);   // RNE
  return (unsigned short)(r >> 16);
}
__device__ __forceinline__ float b2f(unsigned short h){
  union { unsigned u; float f; } v; v.u = ((unsigned)h) << 16; return v.f;
}
// XOR swizzle for [128][128] bf16 tiles (256B rows): kills the G4 32-way
// row-major bank conflict; 16B-unit XOR keeps b128 alignment.
__device__ __forceinline__ unsigned swz(int row, int cbyte){
  return (unsigned)(row*256 + (cbyte ^ ((row & 7) << 4)));
}
__device__ __forceinline__ fv4 mfma16(us8 a, us8 b, fv4 c){
  return __builtin_amdgcn_mfma_f32_16x16x32_bf16(
      __builtin_bit_cast(bv8, a), __builtin_bit_cast(bv8, b), c, 0, 0, 0);
}
// B-fragment: packed so lane l loads its 8 bf16 contiguously (coalesced 1KB/wave).
__device__ __forceinline__ us8 ldB(const unsigned short* Bp, int kb, int ct, int l){
  return *(const us8*)(Bp + (((kb*8 + ct)*64 + l)*8));
}

// ---------------- prep kernels ----------------
__global__ void pt_prep_wd21(const float* __restrict__ Wd2, const float* __restrict__ Wg1,
                             float* __restrict__ Wd21){
  int j = blockIdx.x, i = threadIdx.x;
  float s = 0.f;
  for (int k = 0; k < 128; ++k) s = fmaf(Wd2[i*128 + k], Wg1[k*128 + j], s);
  Wd21[i*128 + j] = s;
}
__global__ void pt_prep_cvec(const float* __restrict__ bd2, const float* __restrict__ Wg1,
                             const float* __restrict__ bg1, float* __restrict__ cv){
  int j = threadIdx.x;
  float s = bg1[j];
  for (int k = 0; k < 128; ++k) s = fmaf(bd2[k], Wg1[k*128 + j], s);
  cv[j] = s;
}
// Pack 10 [128][128] f32 weights into bf16 MFMA-B-fragment order.
// sigma(g,j) = 8g+j used here AND at A-load time => any HW k-permutation cancels.
__global__ void pt_prep_pack(const float* W1, const float* Wq, const float* Wk, const float* Wv,
                             const float* Wg1, const float* Ws, const float* Wd2, const float* Wd21,
                             const float* Wg2, const float* W2, unsigned short* packW){
  const float* srcs[10] = {W1, Wq, Wk, Wv, Wg1, Ws, Wd2, Wd21, Wg2, W2};
  const float* src = srcs[blockIdx.x];
  unsigned short* dst = packW + blockIdx.x * 16384;
  for (int e = threadIdx.x; e < 16384; e += blockDim.x){
    int j = e & 7, lane = (e >> 3) & 63, ct = (e >> 9) & 7, kb = (e >> 12) & 3;
    int row = kb*32 + ((lane >> 4) << 3) + j;   // k index
    int col = ct*16 + (lane & 15);              // n index
    dst[e] = f2b(src[row*128 + col]);
  }
}

// ---------------- per-point projections ----------------
// f = feat@W1+b1; KG=((f@Wk)@Wg1); QG'=((f@Wq)@Wg1)+cvec; V=f@Wv; SH=feat@Ws+bs
__global__ __launch_bounds__(256) void pt_proj(
    const float* __restrict__ feature, const float* __restrict__ b1v,
    const float* __restrict__ bsv, const float* __restrict__ cvec,
    const unsigned short* __restrict__ packW,
    unsigned short* __restrict__ KG, unsigned short* __restrict__ Vv,
    unsigned short* __restrict__ QG, float* __restrict__ SH)
{
  __shared__ alignas(16) char ldsF[32768];
  __shared__ alignas(16) char ldsA[32768];
  __shared__ alignas(16) char ldsT[32768];
  __shared__ float sb1[128], sbs[128], scv[128];
  const unsigned short* W1p  = packW + 0*16384;
  const unsigned short* Wqp  = packW + 1*16384;
  const unsigned short* Wkp  = packW + 2*16384;
  const unsigned short* Wvp  = packW + 3*16384;
  const unsigned short* Wg1p = packW + 4*16384;
  const unsigned short* Wsp  = packW + 5*16384;

  int tid = threadIdx.x;
  int rb = blockIdx.x * 128;
  if (tid < 128){ sb1[tid] = b1v[tid]; sbs[tid] = bsv[tid]; scv[tid] = cvec[tid]; }
  { // stage feature -> bf16 LDS (swizzled)
    int r = tid >> 1, c0 = (tid & 1) * 64;
    const float* src = feature + (long)(rb + r)*ND + c0;
    #pragma unroll
    for (int c = 0; c < 64; c += 2){
      unsigned pk = (unsigned)f2b(src[c]) | ((unsigned)f2b(src[c+1]) << 16);
      *(unsigned*)(ldsF + swz(r, (c0 + c)*2)) = pk;
    }
  }
  __syncthreads();

  int w = tid >> 6, l = tid & 63;
  int row0 = w * 32;
  int arow = l & 15, acb = (l >> 4) << 4;
  int crw = (l >> 4) << 2, ccol = l & 15;
  fv4 acc[2][8];

  auto domm = [&](const char* A, const unsigned short* Bp){
    #pragma unroll
    for (int rt = 0; rt < 2; ++rt)
      #pragma unroll
      for (int ct = 0; ct < 8; ++ct) acc[rt][ct] = fv4{0.f,0.f,0.f,0.f};
    #pragma unroll
    for (int kb = 0; kb < 4; ++kb){
      us8 a0 = *(const us8*)(A + swz(row0 + arow,      kb*64 + acb));
      us8 a1 = *(const us8*)(A + swz(row0 + 16 + arow, kb*64 + acb));
      #pragma unroll
      for (int ct = 0; ct < 8; ++ct){
        us8 bf = ldB(Bp, kb, ct, l);
        acc[0][ct] = mfma16(a0, bf, acc[0][ct]);
        acc[1][ct] = mfma16(a1, bf, acc[1][ct]);
      }
    }
  };
  auto toLds = [&](char* dst, const float* bias){
    #pragma unroll
    for (int rt = 0; rt < 2; ++rt)
      #pragma unroll
      for (int ct = 0; ct < 8; ++ct)
        #pragma unroll
        for (int rg = 0; rg < 4; ++rg){
          int r = row0 + rt*16 + crw + rg, c = ct*16 + ccol;
          float v = acc[rt][ct][rg]; if (bias) v += bias[c];
          *(unsigned short*)(dst + swz(r, c*2)) = f2b(v);
        }
  };
  auto toGlobB = [&](unsigned short* dst, const float* bias){
    #pragma unroll
    for (int rt = 0; rt < 2; ++rt)
      #pragma unroll
      for (int ct = 0; ct < 8; ++ct)
        #pragma unroll
        for (int rg = 0; rg < 4; ++rg){
          int r = row0 + rt*16 + crw + rg, c = ct*16 + ccol;
          float v = acc[rt][ct][rg]; if (bias) v += bias[c];
          dst[(long)(rb + r)*ND + c] = f2b(v);
        }
  };
  auto toGlobF = [&](float* dst, const float* bias){
    #pragma unroll
    for (int rt = 0; rt < 2; ++rt)
      #pragma unroll
      for (int ct = 0; ct < 8; ++ct)
        #pragma unroll
        for (int rg = 0; rg < 4; ++rg){
          int r = row0 + rt*16 + crw + rg, c = ct*16 + ccol;
          dst[(long)(rb + r)*ND + c] = acc[rt][ct][rg] + bias[c];
        }
  };

  // Wave-local rows => no barriers between chained matmuls (in-order LDS per wave).
  domm(ldsF, W1p);  toLds(ldsA, sb1);       // f
  domm(ldsF, Wsp);  toGlobF(SH, sbs);       // shortcut
  domm(ldsA, Wkp);  toLds(ldsT, nullptr);   // f@Wk
  domm(ldsT, Wg1p); toGlobB(KG, nullptr);   // KG
  domm(ldsA, Wqp);  toLds(ldsT, nullptr);   // f@Wq (reuse ldsT, same-wave rows)
  domm(ldsT, Wg1p); toGlobB(QG, scv);       // QG' (+bg1+bd2@Wg1 folded)
  domm(ldsA, Wvp);  toGlobB(Vv, nullptr);   // V
}

// ---------------- main kernel ----------------
// Block = 8 points (128 neighbor rows), 8 waves; wave w owns point w (16 rows).
__global__ __launch_bounds__(512) void pt_main(
    const float* __restrict__ xyz, const int* __restrict__ knn,
    const unsigned short* __restrict__ KG, const unsigned short* __restrict__ Vv,
    const unsigned short* __restrict__ QG, const float* __restrict__ SH,
    const unsigned short* __restrict__ packW,
    const float* __restrict__ Wd1, const float* __restrict__ bd1,
    const float* __restrict__ bd2, const float* __restrict__ bg2,
    const float* __restrict__ b2v, float* __restrict__ outp)
{
  __shared__ alignas(16) char ldsP1[32768];  // relu(xyz@Wd1+bd1) bf16, swz
  __shared__ alignas(16) char ldsHG[32768];  // QG'[p]-KG[idx] -> then G1, bf16, swz
  __shared__ alignas(16) char ldsV[32768];   // gathered V bf16, swz
  __shared__ alignas(16) char ldsAgg[4096];  // [16][128] bf16 A-tile for epilogue
  __shared__ float ldsQG[1024];
  __shared__ int   ldsIdx[128];
  __shared__ float sWd1[384], sbd1[128], sbd2[128], sbg2[128];

  const unsigned short* Wd2p  = packW + 6*16384;
  const unsigned short* Wd21p = packW + 7*16384;
  const unsigned short* Wg2p  = packW + 8*16384;
  const unsigned short* W2p   = packW + 9*16384;

  int tid = threadIdx.x;
  // T1: XCD-aware swizzle (4096 % 8 == 0 -> simple form is bijective)
  int bid = blockIdx.x;
  int wg  = (bid & 7)*512 + (bid >> 3);
  int pb  = wg * 8;               // first global point of block
  int bb  = pb >> 13;             // batch (block never straddles a batch)

  // ---- phase 0: stage indices / QG' / small vectors, zero agg rows 8..15
  if (tid < 128){
    ldsIdx[tid] = (bb << 13) + knn[(long)pb*NK + tid];
    sbd1[tid] = bd1[tid]; sbd2[tid] = bd2[tid]; sbg2[tid] = bg2[tid];
    sWd1[tid] = Wd1[tid]; sWd1[128+tid] = Wd1[128+tid]; sWd1[256+tid] = Wd1[256+tid];
  }
  {
    int e = tid * 2;
    ldsQG[e]   = b2f(QG[(long)pb*ND + e]);
    ldsQG[e+1] = b2f(QG[(long)pb*ND + e + 1]);
  }
  ((unsigned*)ldsAgg)[512 + tid] = 0u;   // bytes 2048..4095 = rows 8..15
  __syncthreads();

  // ---- phase 1: gathers (KG->HG, V) + positional-encoding layer 1
  {
    int r = tid >> 2, qt = tid & 3;            // 4 threads per row, 32 cols each
    int grow = ldsIdx[r];
    const us8* vsrc = (const us8*)(Vv + (long)grow*ND + qt*32);
    const us8* gsrc = (const us8*)(KG + (long)grow*ND + qt*32);
    us8 v0 = vsrc[0], v1 = vsrc[1], v2 = vsrc[2], v3 = vsrc[3];
    us8 g0 = gsrc[0], g1 = gsrc[1], g2 = gsrc[2], g3 = gsrc[3];
    const float* xr = xyz + ((long)pb*NK + r)*3;
    float x0 = xr[0], x1 = xr[1], x2 = xr[2];
    int ds = qt * 32;
    #pragma unroll
    for (int c = 0; c < 32; c += 2){
      int d = ds + c;
      float p0 = fmaxf(0.f, fmaf(x0, sWd1[d],   fmaf(x1, sWd1[128+d],   fmaf(x2, sWd1[256+d],   sbd1[d]))));
      float p1 = fmaxf(0.f, fmaf(x0, sWd1[d+1], fmaf(x1, sWd1[128+d+1], fmaf(x2, sWd1[256+d+1], sbd1[d+1]))));
      *(unsigned*)(ldsP1 + swz(r, d*2)) = (unsigned)f2b(p0) | ((unsigned)f2b(p1) << 16);
    }
    *(us8*)(ldsV + swz(r, qt*64 +  0)) = v0;
    *(us8*)(ldsV + swz(r, qt*64 + 16)) = v1;
    *(us8*)(ldsV + swz(r, qt*64 + 32)) = v2;
    *(us8*)(ldsV + swz(r, qt*64 + 48)) = v3;
    const float* qgr = ldsQG + (r >> 4)*ND + qt*32;
    us8 gv[4] = {g0, g1, g2, g3};
    #pragma unroll
    for (int u = 0; u < 4; ++u){
      us8 hv;
      #pragma unroll
      for (int j = 0; j < 8; ++j) hv[j] = f2b(qgr[u*8 + j] - b2f(gv[u][j]));
      *(us8*)(ldsHG + swz(r, qt*64 + u*16)) = hv;
    }
  }
  __syncthreads();

  // ---- phase 2: per-wave MFMA pipeline for its point
  int w = tid >> 6, l = tid & 63;
  int row0 = w * 16;
  int arow = row0 + (l & 15), acb = (l >> 4) << 4;
  int crow = row0 + ((l >> 4) << 2), ccol = l & 15;

  us8 ap[4];
  #pragma unroll
  for (int kb = 0; kb < 4; ++kb)
    ap[kb] = *(const us8*)(ldsP1 + swz(arow, kb*64 + acb));

  fv4 pg[8], ps[8];
  #pragma unroll
  for (int ct = 0; ct < 8; ++ct){ pg[ct] = fv4{0,0,0,0}; ps[ct] = fv4{0,0,0,0}; }
  #pragma unroll
  for (int kb = 0; kb < 4; ++kb)
    #pragma unroll
    for (int ct = 0; ct < 8; ++ct)
      pg[ct] = mfma16(ap[kb], ldB(Wd21p, kb, ct, l), pg[ct]);   // P1@Wd21
  #pragma unroll
  for (int kb = 0; kb < 4; ++kb)
    #pragma unroll
    for (int ct = 0; ct < 8; ++ct)
      ps[ct] = mfma16(ap[kb], ldB(Wd2p, kb, ct, l), ps[ct]);    // P1@Wd2 (pos, pre-bd2)

  // G1 = relu(P1@Wd21 + QG'-KG)  (in place over ldsHG; same-lane RMW, in-order DS)
  #pragma unroll
  for (int ct = 0; ct < 8; ++ct)
    #pragma unroll
    for (int rg = 0; rg < 4; ++rg){
      int r = crow + rg, c = ct*16 + ccol;
      unsigned short hg = *(unsigned short*)(ldsHG + swz(r, c*2));
      float g = fmaxf(0.f, pg[ct][rg] + b2f(hg));
      *(unsigned short*)(ldsHG + swz(r, c*2)) = f2b(g);
    }
  us8 ag[4];
  #pragma unroll
  for (int kb = 0; kb < 4; ++kb)
    ag[kb] = *(const us8*)(ldsHG + swz(arow, kb*64 + acb));
  fv4 lg[8];
  #pragma unroll
  for (int ct = 0; ct < 8; ++ct) lg[ct] = fv4{0,0,0,0};
  #pragma unroll
  for (int kb = 0; kb < 4; ++kb)
    #pragma unroll
    for (int ct = 0; ct < 8; ++ct)
      lg[ct] = mfma16(ag[kb], ldB(Wg2p, kb, ct, l), lg[ct]);    // G1@Wg2

  // softmax over the 16 neighbor rows (per channel) + aggregation
  const float SC = 0.08838834764831843f;   // 1/sqrt(128)
  #pragma unroll
  for (int ct = 0; ct < 8; ++ct){
    int cbase = ct*16 + ccol;
    float m = -1e30f;
    #pragma unroll
    for (int rg = 0; rg < 4; ++rg){
      float v = (lg[ct][rg] + sbg2[cbase]) * SC;
      lg[ct][rg] = v;
      m = fmaxf(m, v);
    }
    m = fmaxf(m, __shfl_xor(m, 16));
    m = fmaxf(m, __shfl_xor(m, 32));
    float s = 0.f;
    #pragma unroll
    for (int rg = 0; rg < 4; ++rg){ float e = __expf(lg[ct][rg] - m); lg[ct][rg] = e; s += e; }
    s += __shfl_xor(s, 16);
    s += __shfl_xor(s, 32);
    float inv = 1.0f / s;
    float c4 = 0.f;
    #pragma unroll
    for (int rg = 0; rg < 4; ++rg){
      int r = crow + rg;
      float vv = b2f(*(unsigned short*)(ldsV + swz(r, cbase*2)));
      float pe = ps[ct][rg] + sbd2[cbase];
      c4 += lg[ct][rg] * inv * (vv + pe);
    }
    c4 += __shfl_xor(c4, 16);
    c4 += __shfl_xor(c4, 32);
    if (l < 16)
      *(unsigned short*)(ldsAgg + swz(w, (ct*16 + l)*2)) = f2b(c4);
  }
  __syncthreads();

  // ---- epilogue: out = agg@W2 + b2 + shortcut ; wave w -> output cols [16w,16w+16)
  fv4 oo = fv4{0,0,0,0};
  #pragma unroll
  for (int kb = 0; kb < 4; ++kb){
    us8 aa = *(const us8*)(ldsAgg + swz(l & 15, kb*64 + acb));
    oo = mfma16(aa, ldB(W2p, kb, w, l), oo);
  }
  int prow = (l >> 4) << 2;
  if (prow < 8){
    int c = w*16 + (l & 15);
    #pragma unroll
    for (int rg = 0; rg < 4; ++rg){
      long gp = pb + prow + rg;
      outp[gp*ND + c] = oo[rg] + b2v[c] + SH[gp*ND + c];
    }
  }
}

// ---------------- launch ----------------
extern "C" void kernel_launch(void* const* d_in, const int* in_sizes, int n_in,
                              void* d_out, int out_size, void* d_ws, size_t ws_size,
                              hipStream_t stream)
{
  const float* xyz     = (const float*)d_in[0];
  const float* feature = (const float*)d_in[1];
  const int*   knn     = (const int*)d_in[2];
  const float* Wd1 = (const float*)d_in[3];
  const float* bd1 = (const float*)d_in[4];
  const float* Wd2 = (const float*)d_in[5];
  const float* bd2 = (const float*)d_in[6];
  const float* W1  = (const float*)d_in[7];
  const float* b1  = (const float*)d_in[8];
  const float* Wq  = (const float*)d_in[9];
  const float* Wk  = (const float*)d_in[10];
  const float* Wv  = (const float*)d_in[11];
  const float* Wg1 = (const float*)d_in[12];
  const float* bg1 = (const float*)d_in[13];
  const float* Wg2 = (const float*)d_in[14];
  const float* bg2 = (const float*)d_in[15];
  const float* W2  = (const float*)d_in[16];
  const float* b2  = (const float*)d_in[17];
  const float* Ws  = (const float*)d_in[18];
  const float* bs  = (const float*)d_in[19];

  char* ws = (char*)d_ws;
  unsigned short* KGa  = (unsigned short*)(ws);              // [32768][128] bf16
  unsigned short* Va   = (unsigned short*)(ws + 8388608);    // [32768][128] bf16
  unsigned short* QGa  = (unsigned short*)(ws + 16777216);   // [32768][128] bf16
  float*          SHa  = (float*)(ws + 25165824);            // [32768][128] f32
  unsigned short* packW= (unsigned short*)(ws + 41943040);   // 10 x 16384 bf16
  float*          Wd21 = (float*)(ws + 42270720);            // [128][128] f32
  float*          cv   = (float*)(ws + 42336256);            // [128] f32

  pt_prep_wd21<<<128, 128, 0, stream>>>(Wd2, Wg1, Wd21);
  pt_prep_cvec<<<1, 128, 0, stream>>>(bd2, Wg1, bg1, cv);
  pt_prep_pack<<<10, 256, 0, stream>>>(W1, Wq, Wk, Wv, Wg1, Ws, Wd2, Wd21, Wg2, W2, packW);
  pt_proj<<<NPTS/128, 256, 0, stream>>>(feature, b1, bs, cv, packW, KGa, Va, QGa, SHa);
  pt_main<<<NPTS/8, 512, 0, stream>>>(xyz, knn, KGa, Va, QGa, SHa, packW,
                                      Wd1, bd1, bd2, bg2, b2, (float*)d_out);
}

// Round 4
// 363.086 us; speedup vs baseline: 1.1253x; 1.1253x over previous
//
#include <hip/hip_runtime.h>

// Point Transformer block, MI355X/gfx950.  B=4, N=8192, K=16, D=128.
#define NB 4
#define NN 8192
#define NK 16
#define ND 128
#define NPTS (NB*NN)   // 32768 points

typedef __bf16 bv8 __attribute__((ext_vector_type(8)));
typedef unsigned short us8 __attribute__((ext_vector_type(8)));
typedef float fv4 __attribute__((ext_vector_type(4)));
typedef float f32x16 __attribute__((ext_vector_type(16)));
typedef unsigned int u32;

__device__ __forceinline__ unsigned short f2b(float x){
  union { float f; unsigned u; } v; v.f = x;
  unsigned r = v.u + 0x7FFFu + ((v.u >> 16) & 1u);   // RNE
  return (unsigned short)(r >> 16);
}
__device__ __forceinline__ float blo(u32 u){ return __builtin_bit_cast(float, u << 16); }
__device__ __forceinline__ float bhi(u32 u){ return __builtin_bit_cast(float, u & 0xffff0000u); }
__device__ __forceinline__ u32 pkbf(float lo, float hi){
  u32 r; asm("v_cvt_pk_bf16_f32 %0, %1, %2" : "=v"(r) : "v"(lo), "v"(hi)); return r;
}
__device__ __forceinline__ unsigned swz(int row, int cbyte){
  return (unsigned)(row*256 + (cbyte ^ ((row & 7) << 4)));
}
// agg tile swizzle (u16-col units, 8-u16 = 16B granularity; both sides use it)
__device__ __forceinline__ unsigned aggoff(int pt, int c16){
  return (unsigned)(pt*128 + (c16 ^ ((pt & 7) << 3)));
}
__device__ __forceinline__ fv4 mfma16(us8 a, us8 b, fv4 c){
  return __builtin_amdgcn_mfma_f32_16x16x32_bf16(
      __builtin_bit_cast(bv8, a), __builtin_bit_cast(bv8, b), c, 0, 0, 0);
}
__device__ __forceinline__ f32x16 mfma32(us8 a, us8 b, f32x16 c){
  return __builtin_amdgcn_mfma_f32_32x32x16_bf16(
      __builtin_bit_cast(bv8, a), __builtin_bit_cast(bv8, b), c, 0, 0, 0);
}
__device__ __forceinline__ us8 mkb(u32 w0, u32 w1, u32 w2, u32 w3){
  union { u32 w[4]; us8 v; } u; u.w[0]=w0; u.w[1]=w1; u.w[2]=w2; u.w[3]=w3; return u.v;
}
__device__ __forceinline__ f32x16 zf(){
  f32x16 z;
  #pragma unroll
  for (int i=0;i<16;++i) z[i]=0.f;
  return z;
}
// direction-proof 16-lane sum (row_ror butterfly: every lane ends with the total)
__device__ __forceinline__ float rsum16(float v){
  v += __builtin_bit_cast(float, __builtin_amdgcn_update_dpp(0, __builtin_bit_cast(int, v), 0x128, 0xf, 0xf, false));
  v += __builtin_bit_cast(float, __builtin_amdgcn_update_dpp(0, __builtin_bit_cast(int, v), 0x124, 0xf, 0xf, false));
  v += __builtin_bit_cast(float, __builtin_amdgcn_update_dpp(0, __builtin_bit_cast(int, v), 0x122, 0xf, 0xf, false));
  v += __builtin_bit_cast(float, __builtin_amdgcn_update_dpp(0, __builtin_bit_cast(int, v), 0x121, 0xf, 0xf, false));
  return v;
}

// ---------------- prep: fold weights (f32) ----------------
__global__ void pt_prep1(const float* __restrict__ Wk, const float* __restrict__ Wq,
                         const float* __restrict__ Wg1, float* __restrict__ T1, float* __restrict__ T2){
  int b = blockIdx.x;                       // 8 blocks
  const float* A = (b >= 4) ? Wq : Wk;
  float* D = (b >= 4) ? T2 : T1;
  int row = (b & 3)*32 + (threadIdx.x >> 3);
  int c0 = (threadIdx.x & 7)*16;
  float acc[16];
  #pragma unroll
  for (int j=0;j<16;++j) acc[j]=0.f;
  for (int k=0;k<128;++k){
    float a = A[row*128+k];
    const float* g = Wg1 + k*128 + c0;
    #pragma unroll
    for (int j=0;j<16;++j) acc[j] = fmaf(a, g[j], acc[j]);
  }
  #pragma unroll
  for (int j=0;j<16;++j) D[row*128 + c0 + j] = acc[j];
}

__global__ void pt_prep2(const float* __restrict__ W1, const float* __restrict__ Wv,
                         const float* __restrict__ Wd2, const float* __restrict__ Wg1,
                         const float* __restrict__ T1, const float* __restrict__ T2,
                         const float* __restrict__ b1, const float* __restrict__ bd2,
                         const float* __restrict__ bg1, const float* __restrict__ b2,
                         const float* __restrict__ W2,
                         float* __restrict__ WKG, float* __restrict__ WQG,
                         float* __restrict__ WV, float* __restrict__ W21,
                         float* __restrict__ bKG, float* __restrict__ bQG,
                         float* __restrict__ bV, float* __restrict__ b2p)
{
  int b = blockIdx.x;                       // 17 blocks
  if (b < 16){
    int pr = b >> 2;
    const float* A  = (pr==3) ? Wd2 : W1;
    const float* Bm = (pr==0) ? T1 : (pr==1) ? T2 : (pr==2) ? Wv : Wg1;
    float* D        = (pr==0) ? WKG : (pr==1) ? WQG : (pr==2) ? WV : W21;
    int row = (b & 3)*32 + (threadIdx.x >> 3);
    int c0 = (threadIdx.x & 7)*16;
    float acc[16];
    #pragma unroll
    for (int j=0;j<16;++j) acc[j]=0.f;
    for (int k=0;k<128;++k){
      float a = A[row*128+k];
      const float* g = Bm + k*128 + c0;
      #pragma unroll
      for (int j=0;j<16;++j) acc[j] = fmaf(a, g[j], acc[j]);
    }
    #pragma unroll
    for (int j=0;j<16;++j) D[row*128 + c0 + j] = acc[j];
  } else if (threadIdx.x < 128){
    int j = threadIdx.x;
    float s1=0.f, s2=0.f, s3=0.f, s4=0.f;
    for (int k=0;k<128;++k){
      s1 = fmaf(b1[k],  T1[k*128+j],  s1);
      s2 = fmaf(b1[k],  T2[k*128+j],  s2);
      s2 = fmaf(bd2[k], Wg1[k*128+j], s2);
      s3 = fmaf(b1[k],  Wv[k*128+j],  s3);
      s4 = fmaf(bd2[k], W2[k*128+j],  s4);
    }
    bKG[j] = s1;
    bQG[j] = s2 + bg1[j];        // b1@Wq@Wg1 + bd2@Wg1 + bg1
    bV[j]  = s3;
    b2p[j] = b2[j] + s4;         // b2 + bd2@W2 (softmax sums to 1)
  }
}

// ---------------- pack fragments (bf16) ----------------
// std-B (16x16x32, round-1 validated map); ^T-A (32x32x16, k = kb*16 + 8*(l>>5) + j,
// row = mt*32 + (l&31)); same assumed map used by every producer/consumer pair
// => any true HW k-permutation cancels; only the m74-verified C/D layout is load-bearing.
__global__ void pt_pack(const float* __restrict__ WKG, const float* __restrict__ WQG,
                        const float* __restrict__ WV, const float* __restrict__ Ws,
                        const float* __restrict__ W21, const float* __restrict__ Wd2,
                        const float* __restrict__ Wg2, const float* __restrict__ W2,
                        const float* __restrict__ Wd1, const float* __restrict__ bd1,
                        unsigned short* __restrict__ pstd, unsigned short* __restrict__ pT,
                        unsigned short* __restrict__ pD1)
{
  int b = blockIdx.x;   // 9 blocks
  if (b < 4){
    const float* srcs[4] = {WKG, WQG, WV, Ws};
    const float* src = srcs[b];
    unsigned short* dst = pstd + b*16384;
    for (int e = threadIdx.x; e < 16384; e += blockDim.x){
      int j = e&7, lane = (e>>3)&63, ct = (e>>9)&7, kb = (e>>12)&3;
      int row = kb*32 + ((lane>>4)<<3) + j;
      int col = ct*16 + (lane&15);
      dst[e] = f2b(src[row*128+col]);
    }
  } else if (b < 8){
    const float* srcs[4] = {W21, Wd2, Wg2, W2};
    const float* src = srcs[b-4];
    unsigned short* dst = pT + (b-4)*16384;
    for (int e = threadIdx.x; e < 16384; e += blockDim.x){
      int j = e&7, lane = (e>>3)&63, kb = (e>>9)&7, mt = (e>>12)&3;
      int row = mt*32 + (lane&31);               // output channel (A = W^T)
      int k = kb*16 + ((lane>>5)<<3) + j;        // contraction dim
      dst[e] = f2b(src[k*128+row]);
    }
  } else {
    for (int e = threadIdx.x; e < 2048; e += blockDim.x){
      int j = e&7, lane = (e>>3)&63, mt = (e>>9)&3;
      int c = mt*32 + (lane&31);
      int k = ((lane>>5)<<3) + j;
      float v = (k<3) ? Wd1[k*128+c] : ((k==3) ? bd1[c] : 0.f);
      pD1[e] = f2b(v);
    }
  }
}

// ---------------- fused projection GEMM ----------------
// [KG | QG | V | SH] = feat @ [WKG | WQG | WV | Ws] + bias. 1024 blocks (256 rowblk x 4 panels).
__global__ __launch_bounds__(256) void pt_proj(
    const float* __restrict__ feat, const unsigned short* __restrict__ pstd,
    const float* __restrict__ bKG, const float* __restrict__ bQG,
    const float* __restrict__ bV, const float* __restrict__ bs,
    unsigned short* __restrict__ KG, unsigned short* __restrict__ QG,
    unsigned short* __restrict__ Vv, float* __restrict__ SH)
{
  __shared__ alignas(16) char ldsF[32768];
  int tid = threadIdx.x;
  int bid = blockIdx.x;
  int panel = bid & 3;
  int rb = (bid >> 2) * 128;
  {
    int rr = tid>>1, c0 = (tid&1)*64;
    const float* src = feat + (rb+rr)*128 + c0;
    #pragma unroll
    for (int c=0;c<64;c+=4){
      float4 v = *(const float4*)(src + c);
      u32 w0 = (u32)f2b(v.x) | ((u32)f2b(v.y)<<16);
      u32 w1 = (u32)f2b(v.z) | ((u32)f2b(v.w)<<16);
      *(uint2*)(ldsF + swz(rr, (c0+c)*2)) = make_uint2(w0,w1);
    }
  }
  __syncthreads();
  int w = tid>>6, l = tid&63;
  int row0 = w*32;
  int arow = l&15, acb = (l>>4)<<4;
  int crw = (l>>4)<<2, ccol = l&15;
  const unsigned short* Bp = pstd + panel*16384;
  fv4 acc[2][8];
  #pragma unroll
  for (int rt=0;rt<2;++rt)
    #pragma unroll
    for (int ct=0;ct<8;++ct) acc[rt][ct] = fv4{0.f,0.f,0.f,0.f};
  #pragma unroll
  for (int kb=0;kb<4;++kb){
    us8 a0 = *(const us8*)(ldsF + swz(row0+arow,    kb*64+acb));
    us8 a1 = *(const us8*)(ldsF + swz(row0+16+arow, kb*64+acb));
    #pragma unroll
    for (int ct=0;ct<8;++ct){
      us8 bf = *(const us8*)(Bp + ((kb*8+ct)*64 + l)*8);
      acc[0][ct] = mfma16(a0, bf, acc[0][ct]);
      acc[1][ct] = mfma16(a1, bf, acc[1][ct]);
    }
  }
  const float* bias = (panel==0)?bKG:(panel==1)?bQG:(panel==2)?bV:bs;
  if (panel < 3){
    unsigned short* dst = (panel==0)?KG:(panel==1)?QG:Vv;
    #pragma unroll
    for (int rt=0;rt<2;++rt)
      #pragma unroll
      for (int ct=0;ct<8;++ct)
        #pragma unroll
        for (int rg=0;rg<4;++rg){
          int r = row0 + rt*16 + crw + rg, c = ct*16 + ccol;
          dst[(rb+r)*128 + c] = f2b(acc[rt][ct][rg] + bias[c]);
        }
  } else {
    #pragma unroll
    for (int rt=0;rt<2;++rt)
      #pragma unroll
      for (int ct=0;ct<8;++ct)
        #pragma unroll
        for (int rg=0;rg<4;++rg){
          int r = row0 + rt*16 + crw + rg, c = ct*16 + ccol;
          SH[(rb+r)*128 + c] = acc[rt][ct][rg] + bias[c];
        }
  }
}

// ---------------- main: transposed-orientation per-point pipeline ----------------
// 512 thr = 8 waves; wave = 2 points (32 neighbor rows = MFMA N-dim, r = lane&31).
// C-layout (m74): col = l&31 (= r), row(reg) = (reg&3) + 8*(reg>>2) + 4*(l>>5).
__global__ __launch_bounds__(512, 2) void pt_main(
    const int* __restrict__ knn, const float* __restrict__ xyz,
    const unsigned short* __restrict__ KG, const unsigned short* __restrict__ QG,
    const unsigned short* __restrict__ Vv, const float* __restrict__ SH,
    const unsigned short* __restrict__ pT, const unsigned short* __restrict__ pD1,
    const float* __restrict__ b2p, float* __restrict__ outp)
{
  __shared__ unsigned short aggL[32*128];   // 8 KB: rows 0-15 = block points, 16-31 zero
  const unsigned short* pW21T = pT + 0*16384;
  const unsigned short* pWd2T = pT + 1*16384;
  const unsigned short* pWg2T = pT + 2*16384;
  const unsigned short* pW2T  = pT + 3*16384;

  int tid = threadIdx.x;
  int bid = blockIdx.x;
  int wgx = (bid & 7)*256 + (bid >> 3);     // XCD swizzle (2048 = 8*256, bijective)
  int gp0 = wgx * 16;
  int bb  = gp0 >> 13;
  int w = tid >> 6, l = tid & 63;
  int h = l >> 5, r = l & 31, p = r >> 4, n = r & 15;
  int mypt = gp0 + w*2 + p;
  int ptl  = w*2 + p;

  // zero pad rows 16..31 (bytes 4096..8191); ordering vs reads covered by the one barrier
  ((unsigned long long*)aggL)[512 + tid] = 0ull;

  int gidx = (bb << 13) + knn[mypt*16 + n];
  const float* xr = xyz + (mypt*16 + n)*3;
  float xx = xr[0], xy = xr[1], xz = xr[2];

  // ---- P1^T = [Wd1;bd1]^T @ [xyz|1]^T  (K=16, k<4 meaningful)
  u32 bx0 = h ? 0u : pkbf(xx, xy);
  u32 bx1 = h ? 0u : pkbf(xz, 1.0f);
  us8 bX = mkb(bx0, bx1, 0u, 0u);
  f32x16 P1f[4];
  #pragma unroll
  for (int mt=0; mt<4; ++mt){
    us8 aW = *(const us8*)(pD1 + (mt*64 + l)*8);
    P1f[mt] = mfma32(aW, bX, zf());
  }
  u32 pw[4][4][2];
  #pragma unroll
  for (int mt=0; mt<4; ++mt)
    #pragma unroll
    for (int q=0; q<4; ++q)
      #pragma unroll
      for (int wi=0; wi<2; ++wi)
        pw[mt][q][wi] = pkbf(fmaxf(0.f, P1f[mt][4*q+2*wi]),
                             fmaxf(0.f, P1f[mt][4*q+2*wi+1]));

  // ---- build B-frags of P1^T: element j of lane (h) at kb: d = 16kb+8h+j;
  // j<4 from h_src=0 quad q=2(kb&1)+h; j>=4 from h_src=1 same quad (shfl_xor 32)
  u32 Bp[8][4];
  #pragma unroll
  for (int kb=0; kb<8; ++kb){
    int ms = kb>>1, qA = 2*(kb&1), qB = qA+1;
    u32 sA0 = __shfl_xor(pw[ms][qA][0], 32), sA1 = __shfl_xor(pw[ms][qA][1], 32);
    u32 sB0 = __shfl_xor(pw[ms][qB][0], 32), sB1 = __shfl_xor(pw[ms][qB][1], 32);
    Bp[kb][0] = h ? sB0 : pw[ms][qA][0];
    Bp[kb][1] = h ? sB1 : pw[ms][qA][1];
    Bp[kb][2] = h ? pw[ms][qB][0] : sA0;
    Bp[kb][3] = h ? pw[ms][qB][1] : sA1;
  }

  // ---- gather KG (neighbor rows) and QG (own point) directly from global: b64 quads
  uint2 kg[4][4], qg[4][4];
  {
    const unsigned short* kgr = KG + gidx*128;
    const unsigned short* qgr = QG + mypt*128;
    #pragma unroll
    for (int mt=0; mt<4; ++mt)
      #pragma unroll
      for (int q=0; q<4; ++q){
        kg[mt][q] = *(const uint2*)(kgr + 32*mt + 8*q + 4*h);
        qg[mt][q] = *(const uint2*)(qgr + 32*mt + 8*q + 4*h);
      }
  }

  // ---- pg^T = Wd21^T @ P1^T
  f32x16 pg[4];
  #pragma unroll
  for (int mt=0; mt<4; ++mt) pg[mt] = zf();
  #pragma unroll
  for (int kb=0; kb<8; ++kb){
    us8 bfr = mkb(Bp[kb][0], Bp[kb][1], Bp[kb][2], Bp[kb][3]);
    #pragma unroll
    for (int mt=0; mt<4; ++mt){
      us8 a = *(const us8*)(pW21T + ((mt*8+kb)*64 + l)*8);
      pg[mt] = mfma32(a, bfr, pg[mt]);
    }
  }

  // ---- G1 = relu(pg + QG' - KG)  (all at matching per-lane positions) -> bf16 words
  u32 gw[4][4][2];
  #pragma unroll
  for (int mt=0; mt<4; ++mt)
    #pragma unroll
    for (int q=0; q<4; ++q){
      float g0 = fmaxf(0.f, pg[mt][4*q+0] + (blo(qg[mt][q].x) - blo(kg[mt][q].x)));
      float g1 = fmaxf(0.f, pg[mt][4*q+1] + (bhi(qg[mt][q].x) - bhi(kg[mt][q].x)));
      float g2 = fmaxf(0.f, pg[mt][4*q+2] + (blo(qg[mt][q].y) - blo(kg[mt][q].y)));
      float g3 = fmaxf(0.f, pg[mt][4*q+3] + (bhi(qg[mt][q].y) - bhi(kg[mt][q].y)));
      gw[mt][q][0] = pkbf(g0, g1);
      gw[mt][q][1] = pkbf(g2, g3);
    }
  u32 Bg[8][4];
  #pragma unroll
  for (int kb=0; kb<8; ++kb){
    int ms = kb>>1, qA = 2*(kb&1), qB = qA+1;
    u32 sA0 = __shfl_xor(gw[ms][qA][0], 32), sA1 = __shfl_xor(gw[ms][qA][1], 32);
    u32 sB0 = __shfl_xor(gw[ms][qB][0], 32), sB1 = __shfl_xor(gw[ms][qB][1], 32);
    Bg[kb][0] = h ? sB0 : gw[ms][qA][0];
    Bg[kb][1] = h ? sB1 : gw[ms][qA][1];
    Bg[kb][2] = h ? gw[ms][qB][0] : sA0;
    Bg[kb][3] = h ? gw[ms][qB][1] : sA1;
  }

  // ---- V gathers (prefetch under lg mfma)
  uint2 vv[4][4];
  {
    const unsigned short* vr = Vv + gidx*128;
    #pragma unroll
    for (int mt=0; mt<4; ++mt)
      #pragma unroll
      for (int q=0; q<4; ++q)
        vv[mt][q] = *(const uint2*)(vr + 32*mt + 8*q + 4*h);
  }

  // ---- lg^T = Wg2^T @ G1^T   (bg2 and max cancel inside softmax)
  f32x16 lg[4];
  #pragma unroll
  for (int mt=0; mt<4; ++mt) lg[mt] = zf();
  #pragma unroll
  for (int kb=0; kb<8; ++kb){
    us8 bfr = mkb(Bg[kb][0], Bg[kb][1], Bg[kb][2], Bg[kb][3]);
    #pragma unroll
    for (int mt=0; mt<4; ++mt){
      us8 a = *(const us8*)(pWg2T + ((mt*8+kb)*64 + l)*8);
      lg[mt] = mfma32(a, bfr, lg[mt]);
    }
  }

  // ---- per-mt: ps^T tile, exp, neighbor reductions (16-lane DPP), agg -> LDS
  const float SC = 0.08838834764831843f;   // 1/sqrt(128)
  #pragma unroll
  for (int mt=0; mt<4; ++mt){
    f32x16 ps = zf();
    #pragma unroll
    for (int kb=0; kb<8; ++kb){
      us8 a = *(const us8*)(pWd2T + ((mt*8+kb)*64 + l)*8);
      ps = mfma32(a, mkb(Bp[kb][0], Bp[kb][1], Bp[kb][2], Bp[kb][3]), ps);
    }
    float aggv[16];
    #pragma unroll
    for (int q=0; q<4; ++q){
      float wv0 = blo(vv[mt][q].x) + ps[4*q+0];
      float wv1 = bhi(vv[mt][q].x) + ps[4*q+1];
      float wv2 = blo(vv[mt][q].y) + ps[4*q+2];
      float wv3 = bhi(vv[mt][q].y) + ps[4*q+3];
      float e0 = __expf(lg[mt][4*q+0]*SC);
      float e1 = __expf(lg[mt][4*q+1]*SC);
      float e2 = __expf(lg[mt][4*q+2]*SC);
      float e3 = __expf(lg[mt][4*q+3]*SC);
      float s0 = rsum16(e0), s1 = rsum16(e1), s2 = rsum16(e2), s3 = rsum16(e3);
      float m0 = rsum16(e0*wv0), m1 = rsum16(e1*wv1), m2 = rsum16(e2*wv2), m3 = rsum16(e3*wv3);
      aggv[4*q+0] = m0 * __builtin_amdgcn_rcpf(s0);
      aggv[4*q+1] = m1 * __builtin_amdgcn_rcpf(s1);
      aggv[4*q+2] = m2 * __builtin_amdgcn_rcpf(s2);
      aggv[4*q+3] = m3 * __builtin_amdgcn_rcpf(s3);
    }
    if ((l & 15) == 15){            // every lane has the full sums; one writer per (pt,h,c-set)
      #pragma unroll
      for (int q=0; q<4; ++q){
        u32 w0 = pkbf(aggv[4*q+0], aggv[4*q+1]);
        u32 w1 = pkbf(aggv[4*q+2], aggv[4*q+3]);
        *(uint2*)(aggL + aggoff(ptl, 32*mt + 8*q + 4*h)) = make_uint2(w0, w1);
      }
    }
  }
  __syncthreads();

  // ---- epilogue: out^T = W2^T @ agg^T ; + b2' + SH  (waves 0-3, one mt each)
  if (w < 4){
    int mt = w;
    f32x16 o = zf();
    #pragma unroll
    for (int kb=0; kb<8; ++kb){
      us8 a = *(const us8*)(pW2T + ((mt*8+kb)*64 + l)*8);
      us8 bfr = *(const us8*)(aggL + aggoff(l&31, kb*16 + 8*h));
      o = mfma32(a, bfr, o);
    }
    int pt = l & 31;
    if (pt < 16){
      float* orow = outp + (gp0 + pt)*128;
      const float* shrow = SH + (gp0 + pt)*128;
      #pragma unroll
      for (int q=0; q<4; ++q){
        int cb = 32*mt + 8*q + 4*h;
        float4 b4 = *(const float4*)(b2p + cb);
        float4 s4 = *(const float4*)(shrow + cb);
        float4 res;
        res.x = o[4*q+0] + b4.x + s4.x;
        res.y = o[4*q+1] + b4.y + s4.y;
        res.z = o[4*q+2] + b4.z + s4.z;
        res.w = o[4*q+3] + b4.w + s4.w;
        *(float4*)(orow + cb) = res;
      }
    }
  }
}

// ---------------- launch ----------------
extern "C" void kernel_launch(void* const* d_in, const int* in_sizes, int n_in,
                              void* d_out, int out_size, void* d_ws, size_t ws_size,
                              hipStream_t stream)
{
  const float* xyz     = (const float*)d_in[0];
  const float* feature = (const float*)d_in[1];
  const int*   knn     = (const int*)d_in[2];
  const float* Wd1 = (const float*)d_in[3];
  const float* bd1 = (const float*)d_in[4];
  const float* Wd2 = (const float*)d_in[5];
  const float* bd2 = (const float*)d_in[6];
  const float* W1  = (const float*)d_in[7];
  const float* b1  = (const float*)d_in[8];
  const float* Wq  = (const float*)d_in[9];
  const float* Wk  = (const float*)d_in[10];
  const float* Wv  = (const float*)d_in[11];
  const float* Wg1 = (const float*)d_in[12];
  const float* bg1 = (const float*)d_in[13];
  const float* Wg2 = (const float*)d_in[14];
  const float* bg2 = (const float*)d_in[15];  // cancels in softmax (constant over axis)
  const float* W2  = (const float*)d_in[16];
  const float* b2  = (const float*)d_in[17];
  const float* Ws  = (const float*)d_in[18];
  const float* bs  = (const float*)d_in[19];
  (void)bg2;

  char* ws = (char*)d_ws;
  unsigned short* KGa  = (unsigned short*)(ws + 0);          // [32768][128] bf16
  unsigned short* QGa  = (unsigned short*)(ws + 8388608);
  unsigned short* Va   = (unsigned short*)(ws + 16777216);
  float*          SHa  = (float*)(ws + 25165824);            // [32768][128] f32
  unsigned short* PSTD = (unsigned short*)(ws + 41943040);   // 4 x 16384 bf16
  unsigned short* PT   = (unsigned short*)(ws + 42074112);   // 4 x 16384 bf16
  unsigned short* PD1  = (unsigned short*)(ws + 42205184);   // 2048 bf16
  float* T1   = (float*)(ws + 42209280);
  float* T2   = (float*)(ws + 42274816);
  float* WKGf = (float*)(ws + 42340352);
  float* WQGf = (float*)(ws + 42405888);
  float* WVf  = (float*)(ws + 42471424);
  float* W21f = (float*)(ws + 42536960);
  float* bKG  = (float*)(ws + 42602496);
  float* bQG  = (float*)(ws + 42603008);
  float* bV   = (float*)(ws + 42603520);
  float* b2p  = (float*)(ws + 42604032);

  pt_prep1<<<8, 256, 0, stream>>>(Wk, Wq, Wg1, T1, T2);
  pt_prep2<<<17, 256, 0, stream>>>(W1, Wv, Wd2, Wg1, T1, T2, b1, bd2, bg1, b2, W2,
                                   WKGf, WQGf, WVf, W21f, bKG, bQG, bV, b2p);
  pt_pack<<<9, 256, 0, stream>>>(WKGf, WQGf, WVf, Ws, W21f, Wd2, Wg2, W2, Wd1, bd1,
                                 PSTD, PT, PD1);
  pt_proj<<<1024, 256, 0, stream>>>(feature, PSTD, bKG, bQG, bV, bs, KGa, QGa, Va, SHa);
  pt_main<<<2048, 512, 0, stream>>>(knn, xyz, KGa, QGa, Va, SHa, PT, PD1, b2p, (float*)d_out);
}

// Round 6
// 306.530 us; speedup vs baseline: 1.3330x; 1.1845x over previous
//
#include <hip/hip_runtime.h>

// Point Transformer block, MI355X/gfx950.  B=4, N=8192, K=16, D=128.
#define NB 4
#define NN 8192
#define NK 16
#define ND 128
#define NPTS (NB*NN)   // 32768 points

typedef __bf16 bv8 __attribute__((ext_vector_type(8)));
typedef unsigned short us8 __attribute__((ext_vector_type(8)));
typedef float fv4 __attribute__((ext_vector_type(4)));
typedef float f32x16 __attribute__((ext_vector_type(16)));
typedef unsigned int u32;

__device__ __forceinline__ unsigned short f2b(float x){
  union { float f; unsigned u; } v; v.f = x;
  unsigned r = v.u + 0x7FFFu + ((v.u >> 16) & 1u);   // RNE
  return (unsigned short)(r >> 16);
}
__device__ __forceinline__ u32 pkbf(float lo, float hi){
  u32 r; asm("v_cvt_pk_bf16_f32 %0, %1, %2" : "=v"(r) : "v"(lo), "v"(hi)); return r;
}
__device__ __forceinline__ unsigned swz(int row, int cbyte){
  return (unsigned)(row*256 + (cbyte ^ ((row & 7) << 4)));
}
// agg tile swizzle (u16-col units, 8-u16 = 16B granularity; both sides use it)
__device__ __forceinline__ unsigned aggoff(int pt, int c16){
  return (unsigned)(pt*128 + (c16 ^ ((pt & 7) << 3)));
}
__device__ __forceinline__ fv4 mfma16(us8 a, us8 b, fv4 c){
  return __builtin_amdgcn_mfma_f32_16x16x32_bf16(
      __builtin_bit_cast(bv8, a), __builtin_bit_cast(bv8, b), c, 0, 0, 0);
}
__device__ __forceinline__ f32x16 mfma32(us8 a, us8 b, f32x16 c){
  return __builtin_amdgcn_mfma_f32_32x32x16_bf16(
      __builtin_bit_cast(bv8, a), __builtin_bit_cast(bv8, b), c, 0, 0, 0);
}
__device__ __forceinline__ us8 mkb(u32 w0, u32 w1, u32 w2, u32 w3){
  union { u32 w[4]; us8 v; } u; u.w[0]=w0; u.w[1]=w1; u.w[2]=w2; u.w[3]=w3; return u.v;
}
__device__ __forceinline__ f32x16 zf(){
  f32x16 z;
  #pragma unroll
  for (int i=0;i<16;++i) z[i]=0.f;
  return z;
}
// direction-proof 16-lane sum (row_ror butterfly: every lane ends with the total)
__device__ __forceinline__ float rsum16(float v){
  v += __builtin_bit_cast(float, __builtin_amdgcn_update_dpp(0, __builtin_bit_cast(int, v), 0x128, 0xf, 0xf, false));
  v += __builtin_bit_cast(float, __builtin_amdgcn_update_dpp(0, __builtin_bit_cast(int, v), 0x124, 0xf, 0xf, false));
  v += __builtin_bit_cast(float, __builtin_amdgcn_update_dpp(0, __builtin_bit_cast(int, v), 0x122, 0xf, 0xf, false));
  v += __builtin_bit_cast(float, __builtin_amdgcn_update_dpp(0, __builtin_bit_cast(int, v), 0x121, 0xf, 0xf, false));
  return v;
}
// in-place half-swap: a' = {a.lo, b.lo}, b' = {a.hi, b.hi}  (VALU pipe, replaces shfl_xor 32)
__device__ __forceinline__ void plswap(u32& a, u32& b){
  asm("v_permlane32_swap_b32 %0, %1" : "+v"(a), "+v"(b));
}

// ---------------- prep: fold weights (f32, 4x4 reg-tiled) ----------------
__global__ void pt_prep1(const float* __restrict__ Wk, const float* __restrict__ Wq,
                         const float* __restrict__ Wg1, float* __restrict__ T1, float* __restrict__ T2){
  int b = blockIdx.x;                       // 8 blocks
  const float* A = (b >= 4) ? Wq : Wk;
  float* D = (b >= 4) ? T2 : T1;
  int r0 = (b & 3)*32 + (threadIdx.x >> 5)*4;
  int c0 = (threadIdx.x & 31)*4;
  float4 acc[4];
  #pragma unroll
  for (int i=0;i<4;++i) acc[i] = make_float4(0.f,0.f,0.f,0.f);
  for (int k = 0; k < 128; k += 4){
    float4 a[4];
    #pragma unroll
    for (int i=0;i<4;++i) a[i] = *(const float4*)(A + (r0+i)*128 + k);
    #pragma unroll
    for (int kk=0; kk<4; ++kk){
      float4 bv = *(const float4*)(Wg1 + (k+kk)*128 + c0);
      #pragma unroll
      for (int i=0;i<4;++i){
        float av = (kk==0)?a[i].x:(kk==1)?a[i].y:(kk==2)?a[i].z:a[i].w;
        acc[i].x = fmaf(av, bv.x, acc[i].x);
        acc[i].y = fmaf(av, bv.y, acc[i].y);
        acc[i].z = fmaf(av, bv.z, acc[i].z);
        acc[i].w = fmaf(av, bv.w, acc[i].w);
      }
    }
  }
  #pragma unroll
  for (int i=0;i<4;++i) *(float4*)(D + (r0+i)*128 + c0) = acc[i];
}

__global__ void pt_prep2(const float* __restrict__ W1, const float* __restrict__ Wv,
                         const float* __restrict__ Wd2, const float* __restrict__ Wg1,
                         const float* __restrict__ T1, const float* __restrict__ T2,
                         const float* __restrict__ b1, const float* __restrict__ bd2,
                         const float* __restrict__ bg1, const float* __restrict__ b2,
                         const float* __restrict__ W2,
                         float* __restrict__ WKG, float* __restrict__ WQG,
                         float* __restrict__ WV, float* __restrict__ W21,
                         float* __restrict__ bKG, float* __restrict__ bQG,
                         float* __restrict__ bV, float* __restrict__ b2p)
{
  int b = blockIdx.x;                       // 17 blocks
  if (b < 16){
    int pr = b >> 2;
    const float* A  = (pr==3) ? Wd2 : W1;
    const float* Bm = (pr==0) ? T1 : (pr==1) ? T2 : (pr==2) ? Wv : Wg1;
    float* D        = (pr==0) ? WKG : (pr==1) ? WQG : (pr==2) ? WV : W21;
    int r0 = (b & 3)*32 + (threadIdx.x >> 5)*4;
    int c0 = (threadIdx.x & 31)*4;
    float4 acc[4];
    #pragma unroll
    for (int i=0;i<4;++i) acc[i] = make_float4(0.f,0.f,0.f,0.f);
    for (int k = 0; k < 128; k += 4){
      float4 a[4];
      #pragma unroll
      for (int i=0;i<4;++i) a[i] = *(const float4*)(A + (r0+i)*128 + k);
      #pragma unroll
      for (int kk=0; kk<4; ++kk){
        float4 bv = *(const float4*)(Bm + (k+kk)*128 + c0);
        #pragma unroll
        for (int i=0;i<4;++i){
          float av = (kk==0)?a[i].x:(kk==1)?a[i].y:(kk==2)?a[i].z:a[i].w;
          acc[i].x = fmaf(av, bv.x, acc[i].x);
          acc[i].y = fmaf(av, bv.y, acc[i].y);
          acc[i].z = fmaf(av, bv.z, acc[i].z);
          acc[i].w = fmaf(av, bv.w, acc[i].w);
        }
      }
    }
    #pragma unroll
    for (int i=0;i<4;++i) *(float4*)(D + (r0+i)*128 + c0) = acc[i];
  } else if (threadIdx.x < 128){
    int j = threadIdx.x;
    float s1=0.f, s2=0.f, s3=0.f, s4=0.f;
    for (int k=0;k<128;++k){
      s1 = fmaf(b1[k],  T1[k*128+j],  s1);
      s2 = fmaf(b1[k],  T2[k*128+j],  s2);
      s2 = fmaf(bd2[k], Wg1[k*128+j], s2);
      s3 = fmaf(b1[k],  Wv[k*128+j],  s3);
      s4 = fmaf(bd2[k], W2[k*128+j],  s4);
    }
    bKG[j] = s1;
    bQG[j] = s2 + bg1[j];        // b1@Wq@Wg1 + bd2@Wg1 + bg1
    bV[j]  = s3;
    b2p[j] = b2[j] + s4;         // b2 + bd2@W2 (softmax sums to 1)
  }
}

// ---------------- pack fragments (bf16) ----------------
// std-B (16x16x32); ^T-A (32x32x16, k = kb*16 + 8*(l>>5) + j, row = mt*32 + (l&31)).
// Same assumed slot->k map used by every producer/consumer pair => HW k-permutation cancels.
// Wg2 is pre-scaled by SC*log2(e) so main's softmax is a raw exp2.
__global__ void pt_pack(const float* __restrict__ WKG, const float* __restrict__ WQG,
                        const float* __restrict__ WV, const float* __restrict__ Ws,
                        const float* __restrict__ W21, const float* __restrict__ Wd2,
                        const float* __restrict__ Wg2, const float* __restrict__ W2,
                        const float* __restrict__ Wd1, const float* __restrict__ bd1,
                        unsigned short* __restrict__ pstd, unsigned short* __restrict__ pT,
                        unsigned short* __restrict__ pD1)
{
  int b = blockIdx.x;   // 9 blocks
  if (b < 4){
    const float* srcs[4] = {WKG, WQG, WV, Ws};
    const float* src = srcs[b];
    unsigned short* dst = pstd + b*16384;
    for (int e = threadIdx.x; e < 16384; e += blockDim.x){
      int j = e&7, lane = (e>>3)&63, ct = (e>>9)&7, kb = (e>>12)&3;
      int row = kb*32 + ((lane>>4)<<3) + j;
      int col = ct*16 + (lane&15);
      dst[e] = f2b(src[row*128+col]);
    }
  } else if (b < 8){
    const float* srcs[4] = {W21, Wd2, Wg2, W2};
    const float* src = srcs[b-4];
    float scale = (b==6) ? 0.127517445f : 1.0f;   // SC * log2(e) folded into Wg2
    unsigned short* dst = pT + (b-4)*16384;
    for (int e = threadIdx.x; e < 16384; e += blockDim.x){
      int j = e&7, lane = (e>>3)&63, kb = (e>>9)&7, mt = (e>>12)&3;
      int row = mt*32 + (lane&31);               // output channel (A = W^T)
      int k = kb*16 + ((lane>>5)<<3) + j;        // contraction dim
      dst[e] = f2b(src[k*128+row] * scale);
    }
  } else {
    for (int e = threadIdx.x; e < 2048; e += blockDim.x){
      int j = e&7, lane = (e>>3)&63, mt = (e>>9)&3;
      int c = mt*32 + (lane&31);
      int k = ((lane>>5)<<3) + j;
      float v = (k<3) ? Wd1[k*128+c] : ((k==3) ? bd1[c] : 0.f);
      pD1[e] = f2b(v);
    }
  }
}

// ---------------- fused projection GEMM ----------------
// [KG | QG | V | SH] = feat @ [WKG | WQG | WV | Ws] + bias. 1024 blocks (256 rowblk x 4 panels).
__global__ __launch_bounds__(256) void pt_proj(
    const float* __restrict__ feat, const unsigned short* __restrict__ pstd,
    const float* __restrict__ bKG, const float* __restrict__ bQG,
    const float* __restrict__ bV, const float* __restrict__ bs,
    unsigned short* __restrict__ KG, unsigned short* __restrict__ QG,
    unsigned short* __restrict__ Vv, float* __restrict__ SH)
{
  __shared__ alignas(16) char ldsF[32768];
  int tid = threadIdx.x;
  int bid = blockIdx.x;
  int panel = bid & 3;
  int rb = (bid >> 2) * 128;
  {
    int rr = tid>>1, c0 = (tid&1)*64;
    const float* src = feat + (rb+rr)*128 + c0;
    #pragma unroll
    for (int c=0;c<64;c+=4){
      float4 v = *(const float4*)(src + c);
      u32 w0 = (u32)f2b(v.x) | ((u32)f2b(v.y)<<16);
      u32 w1 = (u32)f2b(v.z) | ((u32)f2b(v.w)<<16);
      *(uint2*)(ldsF + swz(rr, (c0+c)*2)) = make_uint2(w0,w1);
    }
  }
  __syncthreads();
  int w = tid>>6, l = tid&63;
  int row0 = w*32;
  int arow = l&15, acb = (l>>4)<<4;
  int crw = (l>>4)<<2, ccol = l&15;
  const unsigned short* Bp = pstd + panel*16384;
  fv4 acc[2][8];
  #pragma unroll
  for (int rt=0;rt<2;++rt)
    #pragma unroll
    for (int ct=0;ct<8;++ct) acc[rt][ct] = fv4{0.f,0.f,0.f,0.f};
  #pragma unroll
  for (int kb=0;kb<4;++kb){
    us8 a0 = *(const us8*)(ldsF + swz(row0+arow,    kb*64+acb));
    us8 a1 = *(const us8*)(ldsF + swz(row0+16+arow, kb*64+acb));
    #pragma unroll
    for (int ct=0;ct<8;++ct){
      us8 bf = *(const us8*)(Bp + ((kb*8+ct)*64 + l)*8);
      acc[0][ct] = mfma16(a0, bf, acc[0][ct]);
      acc[1][ct] = mfma16(a1, bf, acc[1][ct]);
    }
  }
  const float* bias = (panel==0)?bKG:(panel==1)?bQG:(panel==2)?bV:bs;
  if (panel < 3){
    unsigned short* dst = (panel==0)?KG:(panel==1)?QG:Vv;
    #pragma unroll
    for (int rt=0;rt<2;++rt)
      #pragma unroll
      for (int ct=0;ct<8;++ct)
        #pragma unroll
        for (int rg=0;rg<4;++rg){
          int r = row0 + rt*16 + crw + rg, c = ct*16 + ccol;
          dst[(rb+r)*128 + c] = f2b(acc[rt][ct][rg] + bias[c]);
        }
  } else {
    #pragma unroll
    for (int rt=0;rt<2;++rt)
      #pragma unroll
      for (int ct=0;ct<8;++ct)
        #pragma unroll
        for (int rg=0;rg<4;++rg){
          int r = row0 + rt*16 + crw + rg, c = ct*16 + ccol;
          SH[(rb+r)*128 + c] = acc[rt][ct][rg] + bias[c];
        }
  }
}

// ---------------- main: transposed-orientation per-point pipeline ----------------
// 512 thr = 8 waves; wave = 2 points (32 neighbor rows = MFMA N-dim, r = lane&31).
// C-layout (m74): col = l&31 (= r), row(reg) = (reg&3) + 8*(reg>>2) + 4*(l>>5).
// QG/KG/V are folded into the MFMAs via +/-identity A-fragments; their gathered rows
// load directly as contiguous us8 B-fragments (no VALU unpack).
__global__ __launch_bounds__(512, 2) void pt_main(
    const int* __restrict__ knn, const float* __restrict__ xyz,
    const unsigned short* __restrict__ KG, const unsigned short* __restrict__ QG,
    const unsigned short* __restrict__ Vv, const float* __restrict__ SH,
    const unsigned short* __restrict__ pT, const unsigned short* __restrict__ pD1,
    const float* __restrict__ b2p, float* __restrict__ outp)
{
  __shared__ unsigned short aggL[32*128];   // 8 KB: rows 0-15 = block points, 16-31 zero
  const unsigned short* pW21T = pT + 0*16384;
  const unsigned short* pWd2T = pT + 1*16384;
  const unsigned short* pWg2T = pT + 2*16384;   // pre-scaled by SC*log2e
  const unsigned short* pW2T  = pT + 3*16384;

  int tid = threadIdx.x;
  int bid = blockIdx.x;
  int wgx = (bid & 7)*256 + (bid >> 3);     // XCD swizzle (2048 = 8*256, bijective)
  int gp0 = wgx * 16;
  int bb  = gp0 >> 13;
  int w = tid >> 6, l = tid & 63;
  int h = l >> 5, r = l & 31, p = r >> 4, n = r & 15;
  int mypt = gp0 + w*2 + p;
  int ptl  = w*2 + p;

  // zero pad rows 16..31 (bytes 4096..8191); ordering vs reads covered by the one barrier
  ((unsigned long long*)aggL)[512 + tid] = 0ull;

  int gidx = (bb << 13) + knn[mypt*16 + n];
  const float* xr = xyz + (mypt*16 + n)*3;
  float xx = xr[0], xy = xr[1], xz = xr[2];

  // ---- +/-identity A-fragments (assumed A map: k = 8*(l>>5) + j within 16-K, row = l&31)
  int rl = r, hh = h;
  u32 ip0[4], ip1[4], in0[4], in1[4];
  #pragma unroll
  for (int wj=0; wj<4; ++wj){
    int k0 = 8*hh + 2*wj, k1 = k0 + 1;
    ip0[wj] = (rl==k0 ? 0x3F80u : 0u) | (rl==k1 ? 0x3F800000u : 0u);
    in0[wj] = (rl==k0 ? 0xBF80u : 0u) | (rl==k1 ? 0xBF800000u : 0u);
    ip1[wj] = (rl==16+k0 ? 0x3F80u : 0u) | (rl==16+k1 ? 0x3F800000u : 0u);
    in1[wj] = (rl==16+k0 ? 0xBF80u : 0u) | (rl==16+k1 ? 0xBF800000u : 0u);
  }
  us8 Ip0 = mkb(ip0[0],ip0[1],ip0[2],ip0[3]);
  us8 Ip1 = mkb(ip1[0],ip1[1],ip1[2],ip1[3]);
  us8 In0 = mkb(in0[0],in0[1],in0[2],in0[3]);
  us8 In1 = mkb(in1[0],in1[1],in1[2],in1[3]);

  // ---- P1^T = [Wd1;bd1]^T @ [xyz|1]^T  (K=16, k<4 meaningful)
  u32 bx0 = h ? 0u : pkbf(xx, xy);
  u32 bx1 = h ? 0u : pkbf(xz, 1.0f);
  us8 bX = mkb(bx0, bx1, 0u, 0u);
  f32x16 P1f[4];
  #pragma unroll
  for (int mt=0; mt<4; ++mt){
    us8 aW = *(const us8*)(pD1 + (mt*64 + l)*8);
    P1f[mt] = mfma32(aW, bX, zf());
  }
  u32 pw[4][4][2];
  #pragma unroll
  for (int mt=0; mt<4; ++mt)
    #pragma unroll
    for (int q=0; q<4; ++q)
      #pragma unroll
      for (int wi=0; wi<2; ++wi)
        pw[mt][q][wi] = pkbf(fmaxf(0.f, P1f[mt][4*q+2*wi]),
                             fmaxf(0.f, P1f[mt][4*q+2*wi+1]));

  // ---- C->B transpose via permlane32_swap: per kb one swap-pair fills words {0,2},{1,3}
  u32 Bp[8][4];
  #pragma unroll
  for (int kb=0; kb<8; ++kb){
    int ms = kb>>1, qA = 2*(kb&1), qB = qA+1;
    u32 a0 = pw[ms][qA][0], b0 = pw[ms][qB][0];
    u32 a1 = pw[ms][qA][1], b1 = pw[ms][qB][1];
    plswap(a0, b0);
    plswap(a1, b1);
    Bp[kb][0] = a0; Bp[kb][1] = a1; Bp[kb][2] = b0; Bp[kb][3] = b1;
  }

  // ---- pg^T = Wd21^T @ P1^T + I@QG'^T - I@KG^T   (gathered rows as us8 B-frags)
  const unsigned short* qrowb = QG + (long)mypt*ND + 8*h;
  const unsigned short* krowb = KG + (long)gidx*ND + 8*h;
  f32x16 pg[4];
  #pragma unroll
  for (int mt=0; mt<4; ++mt){
    us8 q0 = *(const us8*)(qrowb + 32*mt);
    us8 q1 = *(const us8*)(qrowb + 32*mt + 16);
    us8 k0 = *(const us8*)(krowb + 32*mt);
    us8 k1 = *(const us8*)(krowb + 32*mt + 16);
    f32x16 acc = zf();
    #pragma unroll
    for (int kb=0; kb<8; ++kb){
      us8 a = *(const us8*)(pW21T + ((mt*8+kb)*64 + l)*8);
      acc = mfma32(a, mkb(Bp[kb][0], Bp[kb][1], Bp[kb][2], Bp[kb][3]), acc);
    }
    acc = mfma32(Ip0, q0, acc);
    acc = mfma32(Ip1, q1, acc);
    acc = mfma32(In0, k0, acc);
    acc = mfma32(In1, k1, acc);
    pg[mt] = acc;
  }

  // ---- G1 = relu(pg) -> bf16 words -> B-frags
  u32 gw[4][4][2];
  #pragma unroll
  for (int mt=0; mt<4; ++mt)
    #pragma unroll
    for (int q=0; q<4; ++q){
      gw[mt][q][0] = pkbf(fmaxf(0.f, pg[mt][4*q+0]), fmaxf(0.f, pg[mt][4*q+1]));
      gw[mt][q][1] = pkbf(fmaxf(0.f, pg[mt][4*q+2]), fmaxf(0.f, pg[mt][4*q+3]));
    }
  u32 Bg[8][4];
  #pragma unroll
  for (int kb=0; kb<8; ++kb){
    int ms = kb>>1, qA = 2*(kb&1), qB = qA+1;
    u32 a0 = gw[ms][qA][0], b0 = gw[ms][qB][0];
    u32 a1 = gw[ms][qA][1], b1 = gw[ms][qB][1];
    plswap(a0, b0);
    plswap(a1, b1);
    Bg[kb][0] = a0; Bg[kb][1] = a1; Bg[kb][2] = b0; Bg[kb][3] = b1;
  }

  // ---- lg^T = Wg2s^T @ G1^T   (bg2 and max cancel; SC*log2e pre-folded into Wg2s)
  f32x16 lg[4];
  #pragma unroll
  for (int mt=0; mt<4; ++mt) lg[mt] = zf();
  #pragma unroll
  for (int kb=0; kb<8; ++kb){
    us8 bfr = mkb(Bg[kb][0], Bg[kb][1], Bg[kb][2], Bg[kb][3]);
    #pragma unroll
    for (int mt=0; mt<4; ++mt){
      us8 a = *(const us8*)(pWg2T + ((mt*8+kb)*64 + l)*8);
      lg[mt] = mfma32(a, bfr, lg[mt]);
    }
  }

  // ---- per-mt: ps^T = Wd2^T@P1^T + I@V^T, exp2, 16-lane DPP reductions, agg -> LDS
  const unsigned short* vrowb = Vv + (long)gidx*ND + 8*h;
  us8 v0 = *(const us8*)(vrowb);
  us8 v1 = *(const us8*)(vrowb + 16);
  #pragma unroll
  for (int mt=0; mt<4; ++mt){
    f32x16 ps = zf();
    #pragma unroll
    for (int kb=0; kb<8; ++kb){
      us8 a = *(const us8*)(pWd2T + ((mt*8+kb)*64 + l)*8);
      ps = mfma32(a, mkb(Bp[kb][0], Bp[kb][1], Bp[kb][2], Bp[kb][3]), ps);
    }
    ps = mfma32(Ip0, v0, ps);
    ps = mfma32(Ip1, v1, ps);
    if (mt < 3){                       // prefetch next mt's V frags under the softmax VALU
      v0 = *(const us8*)(vrowb + 32*(mt+1));
      v1 = *(const us8*)(vrowb + 32*(mt+1) + 16);
    }
    float aggv[16];
    #pragma unroll
    for (int q=0; q<4; ++q){
      float e0 = exp2f(lg[mt][4*q+0]);
      float e1 = exp2f(lg[mt][4*q+1]);
      float e2 = exp2f(lg[mt][4*q+2]);
      float e3 = exp2f(lg[mt][4*q+3]);
      float s0 = rsum16(e0), s1 = rsum16(e1), s2 = rsum16(e2), s3 = rsum16(e3);
      float m0 = rsum16(e0*ps[4*q+0]), m1 = rsum16(e1*ps[4*q+1]);
      float m2 = rsum16(e2*ps[4*q+2]), m3 = rsum16(e3*ps[4*q+3]);
      aggv[4*q+0] = m0 * __builtin_amdgcn_rcpf(s0);
      aggv[4*q+1] = m1 * __builtin_amdgcn_rcpf(s1);
      aggv[4*q+2] = m2 * __builtin_amdgcn_rcpf(s2);
      aggv[4*q+3] = m3 * __builtin_amdgcn_rcpf(s3);
    }
    if ((l & 15) == 15){            // every lane has the full sums; one writer per (pt,h,c-set)
      #pragma unroll
      for (int q=0; q<4; ++q){
        u32 w0 = pkbf(aggv[4*q+0], aggv[4*q+1]);
        u32 w1 = pkbf(aggv[4*q+2], aggv[4*q+3]);
        *(uint2*)(aggL + aggoff(ptl, 32*mt + 8*q + 4*h)) = make_uint2(w0, w1);
      }
    }
  }
  __syncthreads();

  // ---- epilogue: out^T = W2^T @ agg^T ; + b2' + SH  (waves 0-3, one mt each)
  if (w < 4){
    int mt = w;
    f32x16 o = zf();
    #pragma unroll
    for (int kb=0; kb<8; ++kb){
      us8 a = *(const us8*)(pW2T + ((mt*8+kb)*64 + l)*8);
      us8 bfr = *(const us8*)(aggL + aggoff(l&31, kb*16 + 8*h));
      o = mfma32(a, bfr, o);
    }
    int pt = l & 31;
    if (pt < 16){
      float* orow = outp + (gp0 + pt)*128;
      const float* shrow = SH + (gp0 + pt)*128;
      #pragma unroll
      for (int q=0; q<4; ++q){
        int cb = 32*mt + 8*q + 4*h;
        float4 b4 = *(const float4*)(b2p + cb);
        float4 s4 = *(const float4*)(shrow + cb);
        float4 res;
        res.x = o[4*q+0] + b4.x + s4.x;
        res.y = o[4*q+1] + b4.y + s4.y;
        res.z = o[4*q+2] + b4.z + s4.z;
        res.w = o[4*q+3] + b4.w + s4.w;
        *(float4*)(orow + cb) = res;
      }
    }
  }
}

// ---------------- launch ----------------
extern "C" void kernel_launch(void* const* d_in, const int* in_sizes, int n_in,
                              void* d_out, int out_size, void* d_ws, size_t ws_size,
                              hipStream_t stream)
{
  const float* xyz     = (const float*)d_in[0];
  const float* feature = (const float*)d_in[1];
  const int*   knn     = (const int*)d_in[2];
  const float* Wd1 = (const float*)d_in[3];
  const float* bd1 = (const float*)d_in[4];
  const float* Wd2 = (const float*)d_in[5];
  const float* bd2 = (const float*)d_in[6];
  const float* W1  = (const float*)d_in[7];
  const float* b1  = (const float*)d_in[8];
  const float* Wq  = (const float*)d_in[9];
  const float* Wk  = (const float*)d_in[10];
  const float* Wv  = (const float*)d_in[11];
  const float* Wg1 = (const float*)d_in[12];
  const float* bg1 = (const float*)d_in[13];
  const float* Wg2 = (const float*)d_in[14];
  const float* bg2 = (const float*)d_in[15];  // cancels in softmax (constant over axis)
  const float* W2  = (const float*)d_in[16];
  const float* b2  = (const float*)d_in[17];
  const float* Ws  = (const float*)d_in[18];
  const float* bs  = (const float*)d_in[19];
  (void)bg2;

  char* ws = (char*)d_ws;
  unsigned short* KGa  = (unsigned short*)(ws + 0);          // [32768][128] bf16
  unsigned short* QGa  = (unsigned short*)(ws + 8388608);
  unsigned short* Va   = (unsigned short*)(ws + 16777216);
  float*          SHa  = (float*)(ws + 25165824);            // [32768][128] f32
  unsigned short* PSTD = (unsigned short*)(ws + 41943040);   // 4 x 16384 bf16
  unsigned short* PT   = (unsigned short*)(ws + 42074112);   // 4 x 16384 bf16
  unsigned short* PD1  = (unsigned short*)(ws + 42205184);   // 2048 bf16
  float* T1   = (float*)(ws + 42209280);
  float* T2   = (float*)(ws + 42274816);
  float* WKGf = (float*)(ws + 42340352);
  float* WQGf = (float*)(ws + 42405888);
  float* WVf  = (float*)(ws + 42471424);
  float* W21f = (float*)(ws + 42536960);
  float* bKG  = (float*)(ws + 42602496);
  float* bQG  = (float*)(ws + 42603008);
  float* bV   = (float*)(ws + 42603520);
  float* b2p  = (float*)(ws + 42604032);

  pt_prep1<<<8, 256, 0, stream>>>(Wk, Wq, Wg1, T1, T2);
  pt_prep2<<<17, 256, 0, stream>>>(W1, Wv, Wd2, Wg1, T1, T2, b1, bd2, bg1, b2, W2,
                                   WKGf, WQGf, WVf, W21f, bKG, bQG, bV, b2p);
  pt_pack<<<9, 256, 0, stream>>>(WKGf, WQGf, WVf, Ws, W21f, Wd2, Wg2, W2, Wd1, bd1,
                                 PSTD, PT, PD1);
  pt_proj<<<1024, 256, 0, stream>>>(feature, PSTD, bKG, bQG, bV, bs, KGa, QGa, Va, SHa);
  pt_main<<<2048, 512, 0, stream>>>(knn, xyz, KGa, QGa, Va, SHa, PT, PD1, b2p, (float*)d_out);
}